// Round 1
// baseline (706.154 us; speedup 1.0000x reference)
//
#include <hip/hip_runtime.h>
#include <hip/hip_bf16.h>

typedef __hip_bfloat16 bf16;
typedef __attribute__((ext_vector_type(8))) short bf16x8;
typedef __attribute__((ext_vector_type(4))) short bf16x4v;
typedef __attribute__((ext_vector_type(4))) float f32x4;

__device__ __forceinline__ void gload_lds16(const void* g, void* l)
{
    __builtin_amdgcn_global_load_lds(
        (const __attribute__((address_space(1))) void*)g,
        (__attribute__((address_space(3))) void*)l, 16, 0, 0);
}

// ---------------------------------------------------------------------------
// MFMA bf16 GEMM: C = epi(A @ Bt^T + bias), K % 128 == 0.
// One-shot K-chunk staging: whole 128-wide K chunk of A and B staged in one
// barrier interval (16 global_load_lds/thread in flight -> single latency
// exposure per chunk instead of 4 with BK=32).
// LDS 128x128 bf16 per operand, XOR-swizzled 16B granules: logical granule g
// of row r lives at byte position (g ^ (r & 7))*16 within the row (rule 21:
// linear global_load_lds dest + pre-swizzled global source + swizzled read).
//   A bf16: global_load_lds staging. A f32: VALU-convert staging (row stride
//   ka, zero-pad k>=ka, optional row gather Aperm masked by apmask).
// ---------------------------------------------------------------------------
template<typename TA, typename TC, int EPI>
__global__ __launch_bounds__(256) void mgemm(
    const TA* __restrict__ A, const bf16* __restrict__ Bt,
    const float* __restrict__ bias, const float* __restrict__ rowscale,
    TC* __restrict__ C, int M, int K, int N, int ka,
    const int* __restrict__ Aperm, unsigned apmask)
{
    __shared__ __align__(16) bf16 As[128 * 128];
    __shared__ __align__(16) bf16 Bs[128 * 128];
    const int tid = threadIdx.x;
    const int lane = tid & 63;
    const int wave = tid >> 6;
    const int col16 = lane & 15;
    const int quad = lane >> 4;
    const int wm = (wave & 1) * 64;
    const int wn = (wave >> 1) * 64;
    const size_t m0 = (size_t)blockIdx.x * 128;
    const int n0 = blockIdx.y * 128;

    f32x4 acc[4][4];
#pragma unroll
    for (int i = 0; i < 4; ++i)
#pragma unroll
        for (int j = 0; j < 4; ++j) acc[i][j] = (f32x4){0.f, 0.f, 0.f, 0.f};

    const int srow = lane >> 4;   // row within the 4-row group of one inst
    const int spos = lane & 15;   // 16B granule position within the row

    for (int kc = 0; kc < K; kc += 128) {
        // ---- stage A (128 rows x 128 k) ----
        if constexpr (sizeof(TA) == 2) {
#pragma unroll
            for (int r = 0; r < 8; ++r) {
                int row = wave * 32 + r * 4 + srow;
                int g = spos ^ (row & 7);
                gload_lds16((const bf16*)A + (m0 + row) * (size_t)K + kc + g * 8,
                            As + (wave * 32 + r * 4) * 128);
            }
        } else {
            const int prow = tid >> 4;    // 0..15
            const int ppos = tid & 15;    // granule position 0..15
#pragma unroll
            for (int rr = 0; rr < 8; ++rr) {
                int row = rr * 16 + prow;
                int g = ppos ^ (row & 7);
                int kg = kc + g * 8;
                size_t arow = Aperm ? (size_t)(unsigned)(Aperm[m0 + row] & (int)apmask)
                                    : (m0 + row);
                const float* ap = (const float*)A + arow * (size_t)ka + kg;
                float4 v0 = make_float4(0.f, 0.f, 0.f, 0.f), v1 = v0;
                if (kg < ka) v0 = *(const float4*)ap;
                if (kg + 4 < ka) v1 = *(const float4*)(ap + 4);
                bf16 t[8] = {__float2bfloat16(v0.x), __float2bfloat16(v0.y),
                             __float2bfloat16(v0.z), __float2bfloat16(v0.w),
                             __float2bfloat16(v1.x), __float2bfloat16(v1.y),
                             __float2bfloat16(v1.z), __float2bfloat16(v1.w)};
                *(bf16x8*)(As + row * 128 + ppos * 8) = *(const bf16x8*)t;
            }
        }
        // ---- stage B (128 rows x 128 k) ----
#pragma unroll
        for (int r = 0; r < 8; ++r) {
            int row = wave * 32 + r * 4 + srow;
            int g = spos ^ (row & 7);
            gload_lds16(Bt + (size_t)(n0 + row) * K + kc + g * 8,
                        Bs + (wave * 32 + r * 4) * 128);
        }
        __syncthreads();

#pragma unroll
        for (int ks = 0; ks < 4; ++ks) {
            bf16x8 a[4], b[4];
#pragma unroll
            for (int i = 0; i < 4; ++i) {
                int row = wm + i * 16 + col16;
                a[i] = *(const bf16x8*)(As + row * 128 + ((ks * 4 + quad) ^ (row & 7)) * 8);
            }
#pragma unroll
            for (int j = 0; j < 4; ++j) {
                int row = wn + j * 16 + col16;
                b[j] = *(const bf16x8*)(Bs + row * 128 + ((ks * 4 + quad) ^ (row & 7)) * 8);
            }
#pragma unroll
            for (int i = 0; i < 4; ++i)
#pragma unroll
                for (int j = 0; j < 4; ++j)
                    acc[i][j] = __builtin_amdgcn_mfma_f32_16x16x32_bf16(a[i], b[j], acc[i][j], 0, 0, 0);
        }
        __syncthreads();
    }

#pragma unroll
    for (int j = 0; j < 4; ++j) {
        int col = n0 + wn + j * 16 + col16;
        float bv = bias ? bias[col] : 0.f;
#pragma unroll
        for (int i = 0; i < 4; ++i) {
#pragma unroll
            for (int r = 0; r < 4; ++r) {
                size_t row = m0 + wm + i * 16 + quad * 4 + r;
                float v = acc[i][j][r] + bv;
                if (EPI == 1) v = v / (1.f + expf(-v));
                if (EPI == 2) v *= rowscale[row];
                if constexpr (sizeof(TC) == 2)
                    ((bf16*)C)[row * (size_t)N + col] = __float2bfloat16(v);
                else
                    ((float*)C)[row * (size_t)N + col] = v;
            }
        }
    }
}

// Fused weight transpose+convert for all 7 weights.
struct CvtArgs {
    const float* in[7];
    bf16* out[7];
    int K[7], Nc[7], Kp[7];
    int cum[8];
};
__global__ __launch_bounds__(256) void cvt_all(CvtArgs a)
{
    int i = blockIdx.x * 256 + threadIdx.x;
#pragma unroll
    for (int s = 0; s < 7; ++s) {
        if (i >= a.cum[s] && i < a.cum[s + 1]) {
            int j = i - a.cum[s];
            int n = j / a.Kp[s], k = j - n * a.Kp[s];
            a.out[s][j] = __float2bfloat16(
                k < a.K[s] ? a.in[s][(size_t)k * a.Nc[s] + n] : 0.f);
        }
    }
}

__global__ __launch_bounds__(256) void cvt_bf16(
    const float4* __restrict__ in, bf16* __restrict__ out, size_t n4)
{
    size_t i = (size_t)blockIdx.x * 256 + threadIdx.x;
    if (i >= n4) return;
    float4 v = in[i];
    bf16 t[4] = {__float2bfloat16(v.x), __float2bfloat16(v.y),
                 __float2bfloat16(v.z), __float2bfloat16(v.w)};
    *(bf16x4v*)(out + i * 4) = *(const bf16x4v*)t;
}

__global__ __launch_bounds__(256) void zero_k(float4* __restrict__ p, size_t n4)
{
    size_t i = (size_t)blockIdx.x * 256 + threadIdx.x;
    if (i < n4) p[i] = make_float4(0.f, 0.f, 0.f, 0.f);
}

// ---- counting sort by target ----
__global__ __launch_bounds__(256) void hist_k(
    const int* __restrict__ ei, int* __restrict__ hist, int E)
{
    int e = blockIdx.x * 256 + threadIdx.x;
    if (e < E) atomicAdd(&hist[ei[e]], 1);
}

// Single block, 256 threads, 128 targets each. Two regions: targets <16384
// start at 0, targets >=16384 start at SLOT1 (fixed slack base).
__global__ __launch_bounds__(256) void scan_k(
    const int* __restrict__ hist, int* __restrict__ off,
    int* __restrict__ cursor, int N, int SLOT1)
{
    __shared__ int ps[257];
    int tid = threadIdx.x;
    int base = tid * 128;
    int s = 0;
    for (int i = 0; i < 128; ++i) s += hist[base + i];
    ps[tid] = s;
    __syncthreads();
    if (tid == 0) {
        int run = 0;
        for (int i = 0; i < 256; ++i) { int t = ps[i]; ps[i] = run; run += t; }
        ps[256] = run;
    }
    __syncthreads();
    int T0 = ps[128];
    int run = ps[tid];
    for (int i = 0; i < 128; ++i) {
        int n = base + i;
        int o = (n < 16384) ? run : SLOT1 + run - T0;
        off[n] = o; cursor[n] = o;
        run += hist[n];
    }
    if (tid == 255) off[N] = SLOT1 + run - T0;
}

__global__ __launch_bounds__(256) void scatter_k(
    const int* __restrict__ ei, const float* __restrict__ uv,
    const float* __restrict__ cut, int* __restrict__ cursor,
    int* __restrict__ perm, int* __restrict__ srcp,
    float* __restrict__ cutp, float* __restrict__ uvp, int E)
{
    int e = blockIdx.x * 256 + threadIdx.x;
    if (e >= E) return;
    int tgt = ei[e];
    int pos = atomicAdd(&cursor[tgt], 1);
    perm[pos] = e;
    srcp[pos] = ei[E + e];
    cutp[pos] = cut[e];
    uvp[pos * 3 + 0] = uv[e * 3 + 0];
    uvp[pos * 3 + 1] = uv[e * 3 + 1];
    uvp[pos * 3 + 2] = uv[e * 3 + 2];
}

// ---- segmented edge reduction: one wave per target, unrolled x4 ----
// Segment length from hist (off[n+1] would cross region slack).
__global__ __launch_bounds__(256) void edge_seg(
    const bf16* __restrict__ x, const bf16* __restrict__ filt,
    const bf16* __restrict__ mub, const int* __restrict__ srcp,
    const float* __restrict__ uvp, const int* __restrict__ off,
    const int* __restrict__ hist,
    const float* __restrict__ q, const float* __restrict__ mu,
    float* __restrict__ outq, float* __restrict__ outmu,
    int t0, int tcount, int base)
{
    int t = blockIdx.x * 4 + (threadIdx.x >> 6);
    if (t >= tcount) return;
    int n = t0 + t;
    int lane = threadIdx.x & 63;
    int h = lane * 2;
    int p0 = off[n];
    int cnt = hist[n];
    int p1 = p0 + cnt;

    float aq0 = 0.f, aq1 = 0.f;
    float am00 = 0.f, am01 = 0.f, am10 = 0.f, am11 = 0.f, am20 = 0.f, am21 = 0.f;

#define EDGE_LOAD(P, S) \
    const bf16* fp##S = filt + (size_t)((P) - base) * 384; \
    int src##S = srcp[P]; \
    const bf16* xp##S = x + (size_t)src##S * 384; \
    const bf16* mp##S = mub + (size_t)src##S * 384; \
    __hip_bfloat162 fq##S = *(const __hip_bfloat162*)(fp##S + h); \
    __hip_bfloat162 fr##S = *(const __hip_bfloat162*)(fp##S + 128 + h); \
    __hip_bfloat162 fm##S = *(const __hip_bfloat162*)(fp##S + 256 + h); \
    __hip_bfloat162 xq##S = *(const __hip_bfloat162*)(xp##S + h); \
    __hip_bfloat162 xr##S = *(const __hip_bfloat162*)(xp##S + 128 + h); \
    __hip_bfloat162 xm##S = *(const __hip_bfloat162*)(xp##S + 256 + h); \
    __hip_bfloat162 m0##S = *(const __hip_bfloat162*)(mp##S + h); \
    __hip_bfloat162 m1##S = *(const __hip_bfloat162*)(mp##S + 128 + h); \
    __hip_bfloat162 m2##S = *(const __hip_bfloat162*)(mp##S + 256 + h); \
    float u0##S = uvp[(P) * 3 + 0]; \
    float u1##S = uvp[(P) * 3 + 1]; \
    float u2##S = uvp[(P) * 3 + 2];

#define EDGE_ACC(S) { \
    float xq0_ = __bfloat162float(xq##S.x) * __bfloat162float(fq##S.x); \
    float xq1_ = __bfloat162float(xq##S.y) * __bfloat162float(fq##S.y); \
    float xr0_ = __bfloat162float(xr##S.x) * __bfloat162float(fr##S.x); \
    float xr1_ = __bfloat162float(xr##S.y) * __bfloat162float(fr##S.y); \
    float xm0_ = __bfloat162float(xm##S.x) * __bfloat162float(fm##S.x); \
    float xm1_ = __bfloat162float(xm##S.y) * __bfloat162float(fm##S.y); \
    aq0 += xq0_; aq1 += xq1_; \
    am00 += fmaf(u0##S, xr0_, __bfloat162float(m0##S.x) * xm0_); \
    am01 += fmaf(u0##S, xr1_, __bfloat162float(m0##S.y) * xm1_); \
    am10 += fmaf(u1##S, xr0_, __bfloat162float(m1##S.x) * xm0_); \
    am11 += fmaf(u1##S, xr1_, __bfloat162float(m1##S.y) * xm1_); \
    am20 += fmaf(u2##S, xr0_, __bfloat162float(m2##S.x) * xm0_); \
    am21 += fmaf(u2##S, xr1_, __bfloat162float(m2##S.y) * xm1_); }

    int p = p0;
    for (; p + 4 <= p1; p += 4) {
        EDGE_LOAD(p, A)
        EDGE_LOAD(p + 1, B)
        EDGE_LOAD(p + 2, C)
        EDGE_LOAD(p + 3, D)
        EDGE_ACC(A)
        EDGE_ACC(B)
        EDGE_ACC(C)
        EDGE_ACC(D)
    }
    for (; p < p1; ++p) {
        EDGE_LOAD(p, T)
        EDGE_ACC(T)
    }
#undef EDGE_LOAD
#undef EDGE_ACC

    float inv = 1.f / fmaxf((float)cnt, 1.f);
    size_t qb = (size_t)n * 128 + h;
    outq[qb]     = q[qb]     + aq0 * inv;
    outq[qb + 1] = q[qb + 1] + aq1 * inv;
    size_t mb = (size_t)n * 384 + h;
    outmu[mb]       = mu[mb]       + am00 * inv;
    outmu[mb + 1]   = mu[mb + 1]   + am01 * inv;
    outmu[mb + 128] = mu[mb + 128] + am10 * inv;
    outmu[mb + 129] = mu[mb + 129] + am11 * inv;
    outmu[mb + 256] = mu[mb + 256] + am20 * inv;
    outmu[mb + 257] = mu[mb + 257] + am21 * inv;
}

// mcat bf16 [3N][256] -> scin=[q|norm] bf16, inner f32. 2 channels/thread.
__global__ __launch_bounds__(256) void mix_pre(
    const bf16* __restrict__ mcat, const float* __restrict__ outq,
    bf16* __restrict__ scin, float* __restrict__ inner, int N)
{
    int i = blockIdx.x * 256 + threadIdx.x;
    if (i >= N * 64) return;
    int n = i >> 6;
    int h = (i & 63) * 2;
    size_t r = (size_t)n * 768;
    __hip_bfloat162 v0 = *(const __hip_bfloat162*)(mcat + r + h);
    __hip_bfloat162 w0 = *(const __hip_bfloat162*)(mcat + r + 128 + h);
    __hip_bfloat162 v1 = *(const __hip_bfloat162*)(mcat + r + 256 + h);
    __hip_bfloat162 w1 = *(const __hip_bfloat162*)(mcat + r + 384 + h);
    __hip_bfloat162 v2 = *(const __hip_bfloat162*)(mcat + r + 512 + h);
    __hip_bfloat162 w2 = *(const __hip_bfloat162*)(mcat + r + 640 + h);
    float v0x = __bfloat162float(v0.x), v0y = __bfloat162float(v0.y);
    float v1x = __bfloat162float(v1.x), v1y = __bfloat162float(v1.y);
    float v2x = __bfloat162float(v2.x), v2y = __bfloat162float(v2.y);
    float nx = sqrtf(v0x * v0x + v1x * v1x + v2x * v2x + 1e-8f);
    float ny = sqrtf(v0y * v0y + v1y * v1y + v2y * v2y + 1e-8f);
    float ix = v0x * __bfloat162float(w0.x) + v1x * __bfloat162float(w1.x)
             + v2x * __bfloat162float(w2.x);
    float iy = v0y * __bfloat162float(w0.y) + v1y * __bfloat162float(w1.y)
             + v2y * __bfloat162float(w2.y);
    *(float2*)(inner + (size_t)n * 128 + h) = make_float2(ix, iy);
    float2 qv = *(const float2*)(outq + (size_t)n * 128 + h);
    __hip_bfloat162 qb; qb.x = __float2bfloat16(qv.x); qb.y = __float2bfloat16(qv.y);
    __hip_bfloat162 nb; nb.x = __float2bfloat16(nx);  nb.y = __float2bfloat16(ny);
    *(__hip_bfloat162*)(scin + (size_t)n * 256 + h) = qb;
    *(__hip_bfloat162*)(scin + (size_t)n * 256 + 128 + h) = nb;
}

// q += dq + dqmu*inner ; mu += mu_w * dmu_scale. 2 channels/thread.
__global__ __launch_bounds__(256) void mix_post(
    const bf16* __restrict__ delta, const float* __restrict__ inner,
    const bf16* __restrict__ mcat,
    float* __restrict__ outq, float* __restrict__ outmu, int N)
{
    int i = blockIdx.x * 256 + threadIdx.x;
    if (i >= N * 64) return;
    int n = i >> 6;
    int h = (i & 63) * 2;
    size_t dr = (size_t)n * 384;
    __hip_bfloat162 dq2  = *(const __hip_bfloat162*)(delta + dr + h);
    __hip_bfloat162 ds2  = *(const __hip_bfloat162*)(delta + dr + 128 + h);
    __hip_bfloat162 dm2  = *(const __hip_bfloat162*)(delta + dr + 256 + h);
    float2 in2 = *(const float2*)(inner + (size_t)n * 128 + h);
    float2* oq = (float2*)(outq + (size_t)n * 128 + h);
    float2 qv = *oq;
    qv.x += __bfloat162float(dq2.x) + __bfloat162float(dm2.x) * in2.x;
    qv.y += __bfloat162float(dq2.y) + __bfloat162float(dm2.y) * in2.y;
    *oq = qv;
    float dsx = __bfloat162float(ds2.x), dsy = __bfloat162float(ds2.y);
    size_t r = (size_t)n * 768;
    size_t mb = (size_t)n * 384 + h;
    __hip_bfloat162 w0 = *(const __hip_bfloat162*)(mcat + r + 128 + h);
    __hip_bfloat162 w1 = *(const __hip_bfloat162*)(mcat + r + 384 + h);
    __hip_bfloat162 w2 = *(const __hip_bfloat162*)(mcat + r + 640 + h);
    float2* om0 = (float2*)(outmu + mb);
    float2* om1 = (float2*)(outmu + mb + 128);
    float2* om2 = (float2*)(outmu + mb + 256);
    float2 a0 = *om0, a1 = *om1, a2 = *om2;
    a0.x += __bfloat162float(w0.x) * dsx; a0.y += __bfloat162float(w0.y) * dsy;
    a1.x += __bfloat162float(w1.x) * dsx; a1.y += __bfloat162float(w1.y) * dsy;
    a2.x += __bfloat162float(w2.x) * dsx; a2.y += __bfloat162float(w2.y) * dsy;
    *om0 = a0; *om1 = a1; *om2 = a2;
}

extern "C" void kernel_launch(void* const* d_in, const int* in_sizes, int n_in,
                              void* d_out, int out_size, void* d_ws, size_t ws_size,
                              hipStream_t stream)
{
    const float* q   = (const float*)d_in[0];
    const float* mu  = (const float*)d_in[1];
    const int*   ei  = (const int*)d_in[2];
    const float* rbf = (const float*)d_in[3];
    const float* uv  = (const float*)d_in[4];
    const float* cut = (const float*)d_in[5];
    const float* Wi1 = (const float*)d_in[6];
    const float* bi1 = (const float*)d_in[7];
    const float* Wi2 = (const float*)d_in[8];
    const float* bi2 = (const float*)d_in[9];
    const float* Wf1 = (const float*)d_in[10];
    const float* bf1 = (const float*)d_in[11];
    const float* Wf2 = (const float*)d_in[12];
    const float* bf2 = (const float*)d_in[13];
    const float* Wv  = (const float*)d_in[14];
    const float* Ws1 = (const float*)d_in[15];
    const float* bs1 = (const float*)d_in[16];
    const float* Ws2 = (const float*)d_in[17];
    const float* bs2 = (const float*)d_in[18];

    const int H = 128;
    const int N = in_sizes[0] / H;   // 32768
    const int E = in_sizes[5];       // 262144
    const int SLOT1 = E / 2 + 4096;  // 135168, %128==0
    (void)n_in; (void)out_size;

    // ---- workspace layout (round-6 proven) ----
    char* ws = (char*)d_ws;
    size_t o = 0;
    auto take = [&](size_t b) { char* p = ws + o; o += (b + 255) & ~(size_t)255; return p; };
    bf16*  xb     = (bf16*)take((size_t)N * 384 * 2);        // 25.2 MB [P1..P3]
    bf16*  mub    = (bf16*)take((size_t)N * 384 * 2);        // 25.2 MB [P3]
    bf16*  filc   = (bf16*)take((size_t)SLOT1 * 384 * 2);    // 103.8 MB [P3]
    bf16*  hf     = (bf16*)take((size_t)SLOT1 * 128 * 2);    // 34.6 MB [P3]
    int*   perm   = (int*)take((size_t)2 * SLOT1 * 4);
    int*   srcp   = (int*)take((size_t)2 * SLOT1 * 4);
    float* cutp   = (float*)take((size_t)2 * SLOT1 * 4);
    float* uvp    = (float*)take((size_t)2 * SLOT1 * 12);
    int*   hist   = (int*)take((size_t)N * 4);
    int*   off    = (int*)take((size_t)(N + 64) * 4);
    int*   cursor = (int*)take((size_t)N * 4);
    bf16*  wts    = (bf16*)take(1100000);
    if (o > ws_size) return;
    // P5 aliases (xb/mub/filc dead): 134.3 MB < 188.8 MB transient region
    bf16*  mcat  = (bf16*)ws;
    bf16*  scin  = mcat + (size_t)N * 768;
    float* inner = (float*)(scin + (size_t)N * 256);
    bf16*  s1    = (bf16*)(inner + (size_t)N * 128);
    bf16*  delta = s1 + (size_t)N * 384;

    bf16* Wi1t = wts;             // [384][128]
    bf16* Wi2t = Wi1t + 49152;    // [384][384]
    bf16* Wf1t = Wi2t + 147456;   // [128][128]  (K padded 20 -> 128)
    bf16* Wf2t = Wf1t + 16384;    // [384][128]
    bf16* Wvt  = Wf2t + 49152;    // [256][128]
    bf16* Ws1t = Wvt  + 32768;    // [384][256]
    bf16* Ws2t = Ws1t + 98304;    // [384][384]

    float* outq  = (float*)d_out;
    float* outmu = outq + (size_t)N * 128;

    dim3 blk(256);

    // ---- P0: weights -> bf16 transposed; mu -> bf16 ----
    {
        CvtArgs a;
        const float* wi[7] = {Wi1, Wi2, Wf1, Wf2, Wv, Ws1, Ws2};
        bf16* wo[7] = {Wi1t, Wi2t, Wf1t, Wf2t, Wvt, Ws1t, Ws2t};
        int K[7]  = {128, 384, 20, 128, 128, 256, 384};
        int Nc[7] = {384, 384, 128, 384, 256, 384, 384};
        int Kp[7] = {128, 384, 128, 128, 128, 256, 384};
        int c = 0;
        for (int s = 0; s < 7; ++s) {
            a.in[s] = wi[s]; a.out[s] = wo[s];
            a.K[s] = K[s]; a.Nc[s] = Nc[s]; a.Kp[s] = Kp[s];
            a.cum[s] = c; c += Nc[s] * Kp[s];
        }
        a.cum[7] = c;
        cvt_all<<<dim3((c + 255) / 256), blk, 0, stream>>>(a);
        cvt_bf16<<<dim3((unsigned)((size_t)N * 384 / 4 / 256)), blk, 0, stream>>>(
            (const float4*)mu, mub, (size_t)N * 384 / 4);
    }

    // ---- P1: interaction MLP (full) ----
    {
        bf16* x1 = filc;   // scratch
        mgemm<float, bf16, 1><<<dim3(N / 128, 3), blk, 0, stream>>>(
            q, Wi1t, bi1, nullptr, x1, N, 128, 384, 128, nullptr, 0);
        mgemm<bf16, bf16, 0><<<dim3(N / 128, 3), blk, 0, stream>>>(
            x1, Wi2t, bi2, nullptr, xb, N, 384, 384, 0, nullptr, 0);
    }

    // ---- PS: counting sort by target (only hist needs zeroing; perm slack is
    // handled by the E-1 gather mask, cutp slack feeds never-read filc rows) ----
    zero_k<<<dim3((N / 4 + 255) / 256), blk, 0, stream>>>((float4*)hist, N / 4);
    hist_k<<<dim3(E / 256), blk, 0, stream>>>(ei, hist, E);
    scan_k<<<dim3(1), blk, 0, stream>>>(hist, off, cursor, N, SLOT1);
    scatter_k<<<dim3(E / 256), blk, 0, stream>>>(ei, uv, cut, cursor,
                                                 perm, srcp, cutp, uvp, E);

    // ---- P3: filter GEMMs (sorted order) + segmented edge reduce, 2 chunks ----
    for (int c = 0; c < 2; ++c) {
        int base = c * SLOT1;
        mgemm<float, bf16, 1><<<dim3(SLOT1 / 128, 1), blk, 0, stream>>>(
            rbf, Wf1t, bf1, nullptr, hf, SLOT1, 128, 128, 20,
            perm + base, (unsigned)(E - 1));
        mgemm<bf16, bf16, 2><<<dim3(SLOT1 / 128, 3), blk, 0, stream>>>(
            hf, Wf2t, bf2, cutp + base, filc, SLOT1, 128, 384, 0, nullptr, 0);
        edge_seg<<<dim3(16384 / 4), blk, 0, stream>>>(
            xb, filc, mub, srcp, uvp, off, hist, q, mu, outq, outmu,
            c * 16384, 16384, base);
    }

    // ---- P5: mixing (full) ----
    mgemm<float, bf16, 0><<<dim3(3 * N / 128, 2), blk, 0, stream>>>(
        outmu, Wvt, nullptr, nullptr, mcat, 3 * N, 128, 256, 128, nullptr, 0);
    mix_pre<<<dim3(N * 64 / 256), blk, 0, stream>>>(mcat, outq, scin, inner, N);
    mgemm<bf16, bf16, 1><<<dim3(N / 128, 3), blk, 0, stream>>>(
        scin, Ws1t, bs1, nullptr, s1, N, 256, 384, 0, nullptr, 0);
    mgemm<bf16, bf16, 0><<<dim3(N / 128, 3), blk, 0, stream>>>(
        s1, Ws2t, bs2, nullptr, delta, N, 384, 384, 0, nullptr, 0);
    mix_post<<<dim3(N * 64 / 256), blk, 0, stream>>>(delta, inner, mcat,
                                                     outq, outmu, N);
}

// Round 2
// 656.528 us; speedup vs baseline: 1.0756x; 1.0756x over previous
//
#include <hip/hip_runtime.h>
#include <hip/hip_bf16.h>

typedef __hip_bfloat16 bf16;
typedef __attribute__((ext_vector_type(8))) short bf16x8;
typedef __attribute__((ext_vector_type(4))) short bf16x4v;
typedef __attribute__((ext_vector_type(4))) float f32x4;

__device__ __forceinline__ void gload_lds16(const void* g, void* l)
{
    __builtin_amdgcn_global_load_lds(
        (const __attribute__((address_space(1))) void*)g,
        (__attribute__((address_space(3))) void*)l, 16, 0, 0);
}

// ---------------------------------------------------------------------------
// MFMA bf16 GEMM: C = epi(A @ Bt^T + bias)
//   BK=32 K-chunks, issue-early double-buffered LDS (2-phase): chunk t+1's
//   global_load_lds are issued BEFORE chunk t's ds_read+MFMA, so the
//   __syncthreads vmcnt-drain only pays the un-hidden remainder of the HBM
//   latency. LDS 32 KB -> ~5 blocks/CU retained (round-1 lesson: 64 KB
//   one-shot staging halved residency and regressed).
//   A f32 path: T14 split — float4 loads for t+1 issued pre-MFMA, cvt+ds_write
//   post-MFMA (row stride ka, zero-pad k>=ka, optional gather Aperm&apmask).
// ---------------------------------------------------------------------------
template<typename TA, typename TC, int EPI>
__global__ __launch_bounds__(256) void mgemm(
    const TA* __restrict__ A, const bf16* __restrict__ Bt,
    const float* __restrict__ bias, const float* __restrict__ rowscale,
    TC* __restrict__ C, int M, int K, int N, int ka,
    const int* __restrict__ Aperm, unsigned apmask)
{
    __shared__ __align__(16) bf16 As[2][128 * 32];
    __shared__ __align__(16) bf16 Bs[2][128 * 32];
    const int tid = threadIdx.x;
    const int lane = tid & 63;
    const int wave = tid >> 6;
    const int col16 = lane & 15;
    const int quad = lane >> 4;
    const int wm = (wave & 1) * 64;
    const int wn = (wave >> 1) * 64;
    const size_t m0 = (size_t)blockIdx.x * 128;
    const int n0 = blockIdx.y * 128;

    f32x4 acc[4][4];
#pragma unroll
    for (int i = 0; i < 4; ++i)
#pragma unroll
        for (int j = 0; j < 4; ++j) acc[i][j] = (f32x4){0.f, 0.f, 0.f, 0.f};

    const int rbase = wave * 32;
    const int srow = lane >> 2;
    const int schk = lane & 3;

    // bf16-A staging: async direct-to-LDS
    auto stageA16 = [&](int buf, int k0) {
        const bf16* g0 = (const bf16*)A + (m0 + rbase + srow) * (size_t)K + k0 + schk * 8;
        gload_lds16(g0, As[buf] + rbase * 32);
        gload_lds16(g0 + 16 * (size_t)K, As[buf] + (rbase + 16) * 32);
    };
    auto stageB = [&](int buf, int k0) {
        const bf16* g0 = Bt + (size_t)(n0 + rbase + srow) * K + k0 + schk * 8;
        gload_lds16(g0, Bs[buf] + rbase * 32);
        gload_lds16(g0 + 16 * (size_t)K, Bs[buf] + (rbase + 16) * 32);
    };
    // f32-A staging, split into load (issue early) and write (after compute)
    float4 pre[4];
    auto loadA32 = [&](int k0) {
#pragma unroll
        for (int r = 0; r < 4; ++r) {
            int p = tid + 256 * r;
            int row = p >> 3, kp = p & 7;
            int kg = k0 + kp * 4;
            size_t arow = Aperm ? (size_t)(unsigned)(Aperm[m0 + row] & (int)apmask)
                                : (m0 + row);
            float4 v = make_float4(0.f, 0.f, 0.f, 0.f);
            if (kg < ka) v = *(const float4*)((const float*)A + arow * (size_t)ka + kg);
            pre[r] = v;
        }
    };
    auto writeA32 = [&](int buf) {
#pragma unroll
        for (int r = 0; r < 4; ++r) {
            int p = tid + 256 * r;
            int row = p >> 3, kp = p & 7;
            float4 v = pre[r];
            bf16 t[4] = {__float2bfloat16(v.x), __float2bfloat16(v.y),
                         __float2bfloat16(v.z), __float2bfloat16(v.w)};
            *(bf16x4v*)(As[buf] + row * 32 + kp * 4) = *(const bf16x4v*)t;
        }
    };

    // prologue: stage chunk 0 into buffer 0
    if constexpr (sizeof(TA) == 2) {
        stageA16(0, 0);
    } else {
        loadA32(0);
        writeA32(0);
    }
    stageB(0, 0);
    __syncthreads();

    const int nk = K >> 5;
    for (int t = 0; t < nk; ++t) {
        const int cur = t & 1;
        const bool more = (t + 1 < nk);
        if (more) {
            if constexpr (sizeof(TA) == 2) stageA16(cur ^ 1, (t + 1) * 32);
            else                           loadA32((t + 1) * 32);
            stageB(cur ^ 1, (t + 1) * 32);
        }

        bf16x8 a[4], b[4];
#pragma unroll
        for (int i = 0; i < 4; ++i)
            a[i] = *(const bf16x8*)(As[cur] + (wm + i * 16 + col16) * 32 + quad * 8);
#pragma unroll
        for (int j = 0; j < 4; ++j)
            b[j] = *(const bf16x8*)(Bs[cur] + (wn + j * 16 + col16) * 32 + quad * 8);
#pragma unroll
        for (int i = 0; i < 4; ++i)
#pragma unroll
            for (int j = 0; j < 4; ++j)
                acc[i][j] = __builtin_amdgcn_mfma_f32_16x16x32_bf16(a[i], b[j], acc[i][j], 0, 0, 0);

        if constexpr (sizeof(TA) != 2) {
            if (more) writeA32(cur ^ 1);
        }
        __syncthreads();
    }

#pragma unroll
    for (int j = 0; j < 4; ++j) {
        int col = n0 + wn + j * 16 + col16;
        float bv = bias ? bias[col] : 0.f;
#pragma unroll
        for (int i = 0; i < 4; ++i) {
#pragma unroll
            for (int r = 0; r < 4; ++r) {
                size_t row = m0 + wm + i * 16 + quad * 4 + r;
                float v = acc[i][j][r] + bv;
                if (EPI == 1) v = v / (1.f + expf(-v));
                if (EPI == 2) v *= rowscale[row];
                if constexpr (sizeof(TC) == 2)
                    ((bf16*)C)[row * (size_t)N + col] = __float2bfloat16(v);
                else
                    ((float*)C)[row * (size_t)N + col] = v;
            }
        }
    }
}

// Fused weight transpose+convert for all 7 weights.
struct CvtArgs {
    const float* in[7];
    bf16* out[7];
    int K[7], Nc[7], Kp[7];
    int cum[8];
};
__global__ __launch_bounds__(256) void cvt_all(CvtArgs a)
{
    int i = blockIdx.x * 256 + threadIdx.x;
#pragma unroll
    for (int s = 0; s < 7; ++s) {
        if (i >= a.cum[s] && i < a.cum[s + 1]) {
            int j = i - a.cum[s];
            int n = j / a.Kp[s], k = j - n * a.Kp[s];
            a.out[s][j] = __float2bfloat16(
                k < a.K[s] ? a.in[s][(size_t)k * a.Nc[s] + n] : 0.f);
        }
    }
}

__global__ __launch_bounds__(256) void cvt_bf16(
    const float4* __restrict__ in, bf16* __restrict__ out, size_t n4)
{
    size_t i = (size_t)blockIdx.x * 256 + threadIdx.x;
    if (i >= n4) return;
    float4 v = in[i];
    bf16 t[4] = {__float2bfloat16(v.x), __float2bfloat16(v.y),
                 __float2bfloat16(v.z), __float2bfloat16(v.w)};
    *(bf16x4v*)(out + i * 4) = *(const bf16x4v*)t;
}

__global__ __launch_bounds__(256) void zero_k(float4* __restrict__ p, size_t n4)
{
    size_t i = (size_t)blockIdx.x * 256 + threadIdx.x;
    if (i < n4) p[i] = make_float4(0.f, 0.f, 0.f, 0.f);
}

// ---- counting sort by target ----
__global__ __launch_bounds__(256) void hist_k(
    const int* __restrict__ ei, int* __restrict__ hist, int E)
{
    int e = blockIdx.x * 256 + threadIdx.x;
    if (e < E) atomicAdd(&hist[ei[e]], 1);
}

// Single block, 256 threads, 128 targets each. Two regions: targets <16384
// start at 0, targets >=16384 start at SLOT1 (fixed slack base).
__global__ __launch_bounds__(256) void scan_k(
    const int* __restrict__ hist, int* __restrict__ off,
    int* __restrict__ cursor, int N, int SLOT1)
{
    __shared__ int ps[257];
    int tid = threadIdx.x;
    int base = tid * 128;
    int s = 0;
    for (int i = 0; i < 128; ++i) s += hist[base + i];
    ps[tid] = s;
    __syncthreads();
    if (tid == 0) {
        int run = 0;
        for (int i = 0; i < 256; ++i) { int t = ps[i]; ps[i] = run; run += t; }
        ps[256] = run;
    }
    __syncthreads();
    int T0 = ps[128];
    int run = ps[tid];
    for (int i = 0; i < 128; ++i) {
        int n = base + i;
        int o = (n < 16384) ? run : SLOT1 + run - T0;
        off[n] = o; cursor[n] = o;
        run += hist[n];
    }
    if (tid == 255) off[N] = SLOT1 + run - T0;
}

__global__ __launch_bounds__(256) void scatter_k(
    const int* __restrict__ ei, const float* __restrict__ uv,
    const float* __restrict__ cut, int* __restrict__ cursor,
    int* __restrict__ perm, int* __restrict__ srcp,
    float* __restrict__ cutp, float* __restrict__ uvp, int E)
{
    int e = blockIdx.x * 256 + threadIdx.x;
    if (e >= E) return;
    int tgt = ei[e];
    int pos = atomicAdd(&cursor[tgt], 1);
    perm[pos] = e;
    srcp[pos] = ei[E + e];
    cutp[pos] = cut[e];
    uvp[pos * 3 + 0] = uv[e * 3 + 0];
    uvp[pos * 3 + 1] = uv[e * 3 + 1];
    uvp[pos * 3 + 2] = uv[e * 3 + 2];
}

// ---- segmented edge reduction: one wave per target, unrolled x2 ----
// Segment length from hist (off[n+1] would cross region slack).
__global__ __launch_bounds__(256) void edge_seg(
    const bf16* __restrict__ x, const bf16* __restrict__ filt,
    const bf16* __restrict__ mub, const int* __restrict__ srcp,
    const float* __restrict__ uvp, const int* __restrict__ off,
    const int* __restrict__ hist,
    const float* __restrict__ q, const float* __restrict__ mu,
    float* __restrict__ outq, float* __restrict__ outmu,
    int t0, int tcount, int base)
{
    int t = blockIdx.x * 4 + (threadIdx.x >> 6);
    if (t >= tcount) return;
    int n = t0 + t;
    int lane = threadIdx.x & 63;
    int h = lane * 2;
    int p0 = off[n];
    int cnt = hist[n];
    int p1 = p0 + cnt;

    float aq0 = 0.f, aq1 = 0.f;
    float am00 = 0.f, am01 = 0.f, am10 = 0.f, am11 = 0.f, am20 = 0.f, am21 = 0.f;

#define EDGE_LOAD(P, S) \
    const bf16* fp##S = filt + (size_t)((P) - base) * 384; \
    int src##S = srcp[P]; \
    const bf16* xp##S = x + (size_t)src##S * 384; \
    const bf16* mp##S = mub + (size_t)src##S * 384; \
    __hip_bfloat162 fq##S = *(const __hip_bfloat162*)(fp##S + h); \
    __hip_bfloat162 fr##S = *(const __hip_bfloat162*)(fp##S + 128 + h); \
    __hip_bfloat162 fm##S = *(const __hip_bfloat162*)(fp##S + 256 + h); \
    __hip_bfloat162 xq##S = *(const __hip_bfloat162*)(xp##S + h); \
    __hip_bfloat162 xr##S = *(const __hip_bfloat162*)(xp##S + 128 + h); \
    __hip_bfloat162 xm##S = *(const __hip_bfloat162*)(xp##S + 256 + h); \
    __hip_bfloat162 m0##S = *(const __hip_bfloat162*)(mp##S + h); \
    __hip_bfloat162 m1##S = *(const __hip_bfloat162*)(mp##S + 128 + h); \
    __hip_bfloat162 m2##S = *(const __hip_bfloat162*)(mp##S + 256 + h); \
    float u0##S = uvp[(P) * 3 + 0]; \
    float u1##S = uvp[(P) * 3 + 1]; \
    float u2##S = uvp[(P) * 3 + 2];

#define EDGE_ACC(S) { \
    float xq0_ = __bfloat162float(xq##S.x) * __bfloat162float(fq##S.x); \
    float xq1_ = __bfloat162float(xq##S.y) * __bfloat162float(fq##S.y); \
    float xr0_ = __bfloat162float(xr##S.x) * __bfloat162float(fr##S.x); \
    float xr1_ = __bfloat162float(xr##S.y) * __bfloat162float(fr##S.y); \
    float xm0_ = __bfloat162float(xm##S.x) * __bfloat162float(fm##S.x); \
    float xm1_ = __bfloat162float(xm##S.y) * __bfloat162float(fm##S.y); \
    aq0 += xq0_; aq1 += xq1_; \
    am00 += fmaf(u0##S, xr0_, __bfloat162float(m0##S.x) * xm0_); \
    am01 += fmaf(u0##S, xr1_, __bfloat162float(m0##S.y) * xm1_); \
    am10 += fmaf(u1##S, xr0_, __bfloat162float(m1##S.x) * xm0_); \
    am11 += fmaf(u1##S, xr1_, __bfloat162float(m1##S.y) * xm1_); \
    am20 += fmaf(u2##S, xr0_, __bfloat162float(m2##S.x) * xm0_); \
    am21 += fmaf(u2##S, xr1_, __bfloat162float(m2##S.y) * xm1_); }

    int p = p0;
    for (; p + 2 <= p1; p += 2) {
        EDGE_LOAD(p, A)
        EDGE_LOAD(p + 1, B)
        EDGE_ACC(A)
        EDGE_ACC(B)
    }
    if (p < p1) {
        EDGE_LOAD(p, A)
        EDGE_ACC(A)
    }
#undef EDGE_LOAD
#undef EDGE_ACC

    float inv = 1.f / fmaxf((float)cnt, 1.f);
    size_t qb = (size_t)n * 128 + h;
    outq[qb]     = q[qb]     + aq0 * inv;
    outq[qb + 1] = q[qb + 1] + aq1 * inv;
    size_t mb = (size_t)n * 384 + h;
    outmu[mb]       = mu[mb]       + am00 * inv;
    outmu[mb + 1]   = mu[mb + 1]   + am01 * inv;
    outmu[mb + 128] = mu[mb + 128] + am10 * inv;
    outmu[mb + 129] = mu[mb + 129] + am11 * inv;
    outmu[mb + 256] = mu[mb + 256] + am20 * inv;
    outmu[mb + 257] = mu[mb + 257] + am21 * inv;
}

// mcat bf16 [3N][256] -> scin=[q|norm] bf16, inner f32. 2 channels/thread.
__global__ __launch_bounds__(256) void mix_pre(
    const bf16* __restrict__ mcat, const float* __restrict__ outq,
    bf16* __restrict__ scin, float* __restrict__ inner, int N)
{
    int i = blockIdx.x * 256 + threadIdx.x;
    if (i >= N * 64) return;
    int n = i >> 6;
    int h = (i & 63) * 2;
    size_t r = (size_t)n * 768;
    __hip_bfloat162 v0 = *(const __hip_bfloat162*)(mcat + r + h);
    __hip_bfloat162 w0 = *(const __hip_bfloat162*)(mcat + r + 128 + h);
    __hip_bfloat162 v1 = *(const __hip_bfloat162*)(mcat + r + 256 + h);
    __hip_bfloat162 w1 = *(const __hip_bfloat162*)(mcat + r + 384 + h);
    __hip_bfloat162 v2 = *(const __hip_bfloat162*)(mcat + r + 512 + h);
    __hip_bfloat162 w2 = *(const __hip_bfloat162*)(mcat + r + 640 + h);
    float v0x = __bfloat162float(v0.x), v0y = __bfloat162float(v0.y);
    float v1x = __bfloat162float(v1.x), v1y = __bfloat162float(v1.y);
    float v2x = __bfloat162float(v2.x), v2y = __bfloat162float(v2.y);
    float nx = sqrtf(v0x * v0x + v1x * v1x + v2x * v2x + 1e-8f);
    float ny = sqrtf(v0y * v0y + v1y * v1y + v2y * v2y + 1e-8f);
    float ix = v0x * __bfloat162float(w0.x) + v1x * __bfloat162float(w1.x)
             + v2x * __bfloat162float(w2.x);
    float iy = v0y * __bfloat162float(w0.y) + v1y * __bfloat162float(w1.y)
             + v2y * __bfloat162float(w2.y);
    *(float2*)(inner + (size_t)n * 128 + h) = make_float2(ix, iy);
    float2 qv = *(const float2*)(outq + (size_t)n * 128 + h);
    __hip_bfloat162 qb; qb.x = __float2bfloat16(qv.x); qb.y = __float2bfloat16(qv.y);
    __hip_bfloat162 nb; nb.x = __float2bfloat16(nx);  nb.y = __float2bfloat16(ny);
    *(__hip_bfloat162*)(scin + (size_t)n * 256 + h) = qb;
    *(__hip_bfloat162*)(scin + (size_t)n * 256 + 128 + h) = nb;
}

// q += dq + dqmu*inner ; mu += mu_w * dmu_scale. 2 channels/thread.
__global__ __launch_bounds__(256) void mix_post(
    const bf16* __restrict__ delta, const float* __restrict__ inner,
    const bf16* __restrict__ mcat,
    float* __restrict__ outq, float* __restrict__ outmu, int N)
{
    int i = blockIdx.x * 256 + threadIdx.x;
    if (i >= N * 64) return;
    int n = i >> 6;
    int h = (i & 63) * 2;
    size_t dr = (size_t)n * 384;
    __hip_bfloat162 dq2  = *(const __hip_bfloat162*)(delta + dr + h);
    __hip_bfloat162 ds2  = *(const __hip_bfloat162*)(delta + dr + 128 + h);
    __hip_bfloat162 dm2  = *(const __hip_bfloat162*)(delta + dr + 256 + h);
    float2 in2 = *(const float2*)(inner + (size_t)n * 128 + h);
    float2* oq = (float2*)(outq + (size_t)n * 128 + h);
    float2 qv = *oq;
    qv.x += __bfloat162float(dq2.x) + __bfloat162float(dm2.x) * in2.x;
    qv.y += __bfloat162float(dq2.y) + __bfloat162float(dm2.y) * in2.y;
    *oq = qv;
    float dsx = __bfloat162float(ds2.x), dsy = __bfloat162float(ds2.y);
    size_t r = (size_t)n * 768;
    size_t mb = (size_t)n * 384 + h;
    __hip_bfloat162 w0 = *(const __hip_bfloat162*)(mcat + r + 128 + h);
    __hip_bfloat162 w1 = *(const __hip_bfloat162*)(mcat + r + 384 + h);
    __hip_bfloat162 w2 = *(const __hip_bfloat162*)(mcat + r + 640 + h);
    float2* om0 = (float2*)(outmu + mb);
    float2* om1 = (float2*)(outmu + mb + 128);
    float2* om2 = (float2*)(outmu + mb + 256);
    float2 a0 = *om0, a1 = *om1, a2 = *om2;
    a0.x += __bfloat162float(w0.x) * dsx; a0.y += __bfloat162float(w0.y) * dsy;
    a1.x += __bfloat162float(w1.x) * dsx; a1.y += __bfloat162float(w1.y) * dsy;
    a2.x += __bfloat162float(w2.x) * dsx; a2.y += __bfloat162float(w2.y) * dsy;
    *om0 = a0; *om1 = a1; *om2 = a2;
}

extern "C" void kernel_launch(void* const* d_in, const int* in_sizes, int n_in,
                              void* d_out, int out_size, void* d_ws, size_t ws_size,
                              hipStream_t stream)
{
    const float* q   = (const float*)d_in[0];
    const float* mu  = (const float*)d_in[1];
    const int*   ei  = (const int*)d_in[2];
    const float* rbf = (const float*)d_in[3];
    const float* uv  = (const float*)d_in[4];
    const float* cut = (const float*)d_in[5];
    const float* Wi1 = (const float*)d_in[6];
    const float* bi1 = (const float*)d_in[7];
    const float* Wi2 = (const float*)d_in[8];
    const float* bi2 = (const float*)d_in[9];
    const float* Wf1 = (const float*)d_in[10];
    const float* bf1 = (const float*)d_in[11];
    const float* Wf2 = (const float*)d_in[12];
    const float* bf2 = (const float*)d_in[13];
    const float* Wv  = (const float*)d_in[14];
    const float* Ws1 = (const float*)d_in[15];
    const float* bs1 = (const float*)d_in[16];
    const float* Ws2 = (const float*)d_in[17];
    const float* bs2 = (const float*)d_in[18];

    const int H = 128;
    const int N = in_sizes[0] / H;   // 32768
    const int E = in_sizes[5];       // 262144
    const int SLOT1 = E / 2 + 4096;  // 135168, %128==0
    (void)n_in; (void)out_size;

    // ---- workspace layout (round-6 proven) ----
    char* ws = (char*)d_ws;
    size_t o = 0;
    auto take = [&](size_t b) { char* p = ws + o; o += (b + 255) & ~(size_t)255; return p; };
    bf16*  xb     = (bf16*)take((size_t)N * 384 * 2);        // 25.2 MB [P1..P3]
    bf16*  mub    = (bf16*)take((size_t)N * 384 * 2);        // 25.2 MB [P3]
    bf16*  filc   = (bf16*)take((size_t)SLOT1 * 384 * 2);    // 103.8 MB [P3]
    bf16*  hf     = (bf16*)take((size_t)SLOT1 * 128 * 2);    // 34.6 MB [P3]
    int*   perm   = (int*)take((size_t)2 * SLOT1 * 4);
    int*   srcp   = (int*)take((size_t)2 * SLOT1 * 4);
    float* cutp   = (float*)take((size_t)2 * SLOT1 * 4);
    float* uvp    = (float*)take((size_t)2 * SLOT1 * 12);
    int*   hist   = (int*)take((size_t)N * 4);
    int*   off    = (int*)take((size_t)(N + 64) * 4);
    int*   cursor = (int*)take((size_t)N * 4);
    bf16*  wts    = (bf16*)take(1100000);
    if (o > ws_size) return;
    // P5 aliases (xb/mub/filc dead): 134.3 MB < 188.8 MB transient region
    bf16*  mcat  = (bf16*)ws;
    bf16*  scin  = mcat + (size_t)N * 768;
    float* inner = (float*)(scin + (size_t)N * 256);
    bf16*  s1    = (bf16*)(inner + (size_t)N * 128);
    bf16*  delta = s1 + (size_t)N * 384;

    bf16* Wi1t = wts;             // [384][128]
    bf16* Wi2t = Wi1t + 49152;    // [384][384]
    bf16* Wf1t = Wi2t + 147456;   // [128][32]
    bf16* Wf2t = Wf1t + 4096;     // [384][128]
    bf16* Wvt  = Wf2t + 49152;    // [256][128]
    bf16* Ws1t = Wvt  + 32768;    // [384][256]
    bf16* Ws2t = Ws1t + 98304;    // [384][384]

    float* outq  = (float*)d_out;
    float* outmu = outq + (size_t)N * 128;

    dim3 blk(256);

    // ---- P0: weights -> bf16 transposed; mu -> bf16 ----
    {
        CvtArgs a;
        const float* wi[7] = {Wi1, Wi2, Wf1, Wf2, Wv, Ws1, Ws2};
        bf16* wo[7] = {Wi1t, Wi2t, Wf1t, Wf2t, Wvt, Ws1t, Ws2t};
        int K[7]  = {128, 384, 20, 128, 128, 256, 384};
        int Nc[7] = {384, 384, 128, 384, 256, 384, 384};
        int Kp[7] = {128, 384, 32, 128, 128, 256, 384};
        int c = 0;
        for (int s = 0; s < 7; ++s) {
            a.in[s] = wi[s]; a.out[s] = wo[s];
            a.K[s] = K[s]; a.Nc[s] = Nc[s]; a.Kp[s] = Kp[s];
            a.cum[s] = c; c += Nc[s] * Kp[s];
        }
        a.cum[7] = c;
        cvt_all<<<dim3((c + 255) / 256), blk, 0, stream>>>(a);
        cvt_bf16<<<dim3((unsigned)((size_t)N * 384 / 4 / 256)), blk, 0, stream>>>(
            (const float4*)mu, mub, (size_t)N * 384 / 4);
    }

    // ---- P1: interaction MLP (full) ----
    {
        bf16* x1 = filc;   // scratch
        mgemm<float, bf16, 1><<<dim3(N / 128, 3), blk, 0, stream>>>(
            q, Wi1t, bi1, nullptr, x1, N, 128, 384, 128, nullptr, 0);
        mgemm<bf16, bf16, 0><<<dim3(N / 128, 3), blk, 0, stream>>>(
            x1, Wi2t, bi2, nullptr, xb, N, 384, 384, 0, nullptr, 0);
    }

    // ---- PS: counting sort by target (only hist needs zeroing; perm slack is
    // handled by the E-1 gather mask, cutp slack feeds never-read filc rows) ----
    zero_k<<<dim3((N / 4 + 255) / 256), blk, 0, stream>>>((float4*)hist, N / 4);
    hist_k<<<dim3(E / 256), blk, 0, stream>>>(ei, hist, E);
    scan_k<<<dim3(1), blk, 0, stream>>>(hist, off, cursor, N, SLOT1);
    scatter_k<<<dim3(E / 256), blk, 0, stream>>>(ei, uv, cut, cursor,
                                                 perm, srcp, cutp, uvp, E);

    // ---- P3: filter GEMMs (sorted order) + segmented edge reduce, 2 chunks ----
    for (int c = 0; c < 2; ++c) {
        int base = c * SLOT1;
        mgemm<float, bf16, 1><<<dim3(SLOT1 / 128, 1), blk, 0, stream>>>(
            rbf, Wf1t, bf1, nullptr, hf, SLOT1, 32, 128, 20,
            perm + base, (unsigned)(E - 1));
        mgemm<bf16, bf16, 2><<<dim3(SLOT1 / 128, 3), blk, 0, stream>>>(
            hf, Wf2t, bf2, cutp + base, filc, SLOT1, 128, 384, 0, nullptr, 0);
        edge_seg<<<dim3(16384 / 4), blk, 0, stream>>>(
            xb, filc, mub, srcp, uvp, off, hist, q, mu, outq, outmu,
            c * 16384, 16384, base);
    }

    // ---- P5: mixing (full) ----
    mgemm<float, bf16, 0><<<dim3(3 * N / 128, 2), blk, 0, stream>>>(
        outmu, Wvt, nullptr, nullptr, mcat, 3 * N, 128, 256, 128, nullptr, 0);
    mix_pre<<<dim3(N * 64 / 256), blk, 0, stream>>>(mcat, outq, scin, inner, N);
    mgemm<bf16, bf16, 1><<<dim3(N / 128, 3), blk, 0, stream>>>(
        scin, Ws1t, bs1, nullptr, s1, N, 256, 384, 0, nullptr, 0);
    mgemm<bf16, bf16, 0><<<dim3(N / 128, 3), blk, 0, stream>>>(
        s1, Ws2t, bs2, nullptr, delta, N, 384, 384, 0, nullptr, 0);
    mix_post<<<dim3(N * 64 / 256), blk, 0, stream>>>(delta, inner, mcat,
                                                     outq, outmu, N);
}

// Round 3
// 609.542 us; speedup vs baseline: 1.1585x; 1.0771x over previous
//
#include <hip/hip_runtime.h>
#include <hip/hip_bf16.h>

typedef __hip_bfloat16 bf16;
typedef __attribute__((ext_vector_type(8))) short bf16x8;
typedef __attribute__((ext_vector_type(4))) short bf16x4v;
typedef __attribute__((ext_vector_type(4))) float f32x4;

__device__ __forceinline__ void gload_lds16(const void* g, void* l)
{
    __builtin_amdgcn_global_load_lds(
        (const __attribute__((address_space(1))) void*)g,
        (__attribute__((address_space(3))) void*)l, 16, 0, 0);
}

__device__ __forceinline__ float silu_f(float v) { return v / (1.f + expf(-v)); }

// ---------------------------------------------------------------------------
// MFMA bf16 GEMM: C = epi(A @ Bt^T + bias), K % 64 == 0.
// BK=64 single-buffered. LDS rows are 128B (8x16B granules), stored XOR-
// swizzled: LDS[row][p] = global[row][p ^ (row&7)]  (linear global_load_lds
// dest + pre-swizzled global source). Fragment reads use granule
// (s*4+quad)^(row&7) -> 2 lanes/bank = conflict-free (was 8-way at BK=32,
// 1.62M SQ_LDS_BANK_CONFLICT measured).
//   A f32 path: VALU-convert staging with the same swizzle (row stride ka,
//   zero-pad k>=ka).
// ---------------------------------------------------------------------------
template<typename TA, typename TC, int EPI>
__global__ __launch_bounds__(256) void mgemm(
    const TA* __restrict__ A, const bf16* __restrict__ Bt,
    const float* __restrict__ bias, const float* __restrict__ rowscale,
    TC* __restrict__ C, int M, int K, int N, int ka)
{
    __shared__ __align__(16) bf16 As[128 * 64];
    __shared__ __align__(16) bf16 Bs[128 * 64];
    const int tid = threadIdx.x;
    const int lane = tid & 63;
    const int wave = tid >> 6;
    const int col16 = lane & 15;
    const int quad = lane >> 4;
    const int wm = (wave & 1) * 64;
    const int wn = (wave >> 1) * 64;
    const size_t m0 = (size_t)blockIdx.x * 128;
    const int n0 = blockIdx.y * 128;

    f32x4 acc[4][4];
#pragma unroll
    for (int i = 0; i < 4; ++i)
#pragma unroll
        for (int j = 0; j < 4; ++j) acc[i][j] = (f32x4){0.f, 0.f, 0.f, 0.f};

    const int rloc = lane >> 3;      // row within 8-row gload group
    const int gpos = lane & 7;       // granule position within row

    for (int kc = 0; kc < K; kc += 64) {
        // ---- stage A ----
        if constexpr (sizeof(TA) == 2) {
#pragma unroll
            for (int i = 0; i < 4; ++i) {
                int row = wave * 32 + i * 8 + rloc;
                int gs = gpos ^ (row & 7);
                gload_lds16((const bf16*)A + (m0 + row) * (size_t)K + kc + gs * 8,
                            As + (wave * 32 + i * 8) * 64);
            }
        } else {
#pragma unroll
            for (int r = 0; r < 4; ++r) {
                int slot = tid + 256 * r;         // 0..1023
                int row = slot >> 3;              // 0..127
                int gl = slot & 7;                // logical granule
                int gp = gl ^ (row & 7);          // phys granule
                int kg = kc + gl * 8;
                const float* ap = (const float*)A + (m0 + row) * (size_t)ka + kg;
                float4 v0 = make_float4(0.f, 0.f, 0.f, 0.f), v1 = v0;
                if (kg < ka) v0 = *(const float4*)ap;
                if (kg + 4 < ka) v1 = *(const float4*)(ap + 4);
                bf16 t[8] = {__float2bfloat16(v0.x), __float2bfloat16(v0.y),
                             __float2bfloat16(v0.z), __float2bfloat16(v0.w),
                             __float2bfloat16(v1.x), __float2bfloat16(v1.y),
                             __float2bfloat16(v1.z), __float2bfloat16(v1.w)};
                *(bf16x8*)(As + row * 64 + gp * 8) = *(const bf16x8*)t;
            }
        }
        // ---- stage B ----
#pragma unroll
        for (int i = 0; i < 4; ++i) {
            int row = wave * 32 + i * 8 + rloc;
            int gs = gpos ^ (row & 7);
            gload_lds16(Bt + (size_t)(n0 + row) * K + kc + gs * 8,
                        Bs + (wave * 32 + i * 8) * 64);
        }
        __syncthreads();

#pragma unroll
        for (int s = 0; s < 2; ++s) {
            bf16x8 a[4], b[4];
#pragma unroll
            for (int i = 0; i < 4; ++i) {
                int row = wm + i * 16 + col16;
                a[i] = *(const bf16x8*)(As + row * 64 + ((s * 4 + quad) ^ (row & 7)) * 8);
            }
#pragma unroll
            for (int j = 0; j < 4; ++j) {
                int row = wn + j * 16 + col16;
                b[j] = *(const bf16x8*)(Bs + row * 64 + ((s * 4 + quad) ^ (row & 7)) * 8);
            }
#pragma unroll
            for (int i = 0; i < 4; ++i)
#pragma unroll
                for (int j = 0; j < 4; ++j)
                    acc[i][j] = __builtin_amdgcn_mfma_f32_16x16x32_bf16(a[i], b[j], acc[i][j], 0, 0, 0);
        }
        __syncthreads();
    }

#pragma unroll
    for (int j = 0; j < 4; ++j) {
        int col = n0 + wn + j * 16 + col16;
        float bv = bias ? bias[col] : 0.f;
#pragma unroll
        for (int i = 0; i < 4; ++i) {
#pragma unroll
            for (int r = 0; r < 4; ++r) {
                size_t row = m0 + wm + i * 16 + quad * 4 + r;
                float v = acc[i][j][r] + bv;
                if (EPI == 1) v = silu_f(v);
                if (EPI == 2) v *= rowscale[row];
                if constexpr (sizeof(TC) == 2)
                    ((bf16*)C)[row * (size_t)N + col] = __float2bfloat16(v);
                else
                    ((float*)C)[row * (size_t)N + col] = v;
            }
        }
    }
}

// ---------------------------------------------------------------------------
// Fused filter pipeline, one chunk of 128-edge-slot blocks:
//   h = silu(rbf[perm] @ W1t + b1)   (K=20 pad 32, kept in LDS, never to HBM)
//   filc = (h @ W2t + b2) * cutp     (3 col-groups of 128, W2t LDS-staged)
// All LDS tiles XOR-swizzled as in mgemm.
// ---------------------------------------------------------------------------
__global__ __launch_bounds__(256) void fil_fused(
    const float* __restrict__ rbf, const bf16* __restrict__ W1t,
    const float* __restrict__ b1, const bf16* __restrict__ W2t,
    const float* __restrict__ b2, const float* __restrict__ cutp,
    const int* __restrict__ perm, bf16* __restrict__ filc, unsigned apmask)
{
    __shared__ __align__(16) bf16 Ar[128 * 32];   // 8 KB
    __shared__ __align__(16) bf16 W1[128 * 32];   // 8 KB
    __shared__ __align__(16) bf16 Hs[128 * 128];  // 32 KB
    __shared__ __align__(16) bf16 W2[128 * 128];  // 32 KB
    const int tid = threadIdx.x;
    const int lane = tid & 63;
    const int wave = tid >> 6;
    const int col16 = lane & 15;
    const int quad = lane >> 4;
    const int wm = (wave & 1) * 64;
    const int wn = (wave >> 1) * 64;
    const int m0 = blockIdx.x * 128;

    // ---- stage Ar: rbf gather f32->bf16, 4 granules/row, swz (row&3) ----
#pragma unroll
    for (int r = 0; r < 2; ++r) {
        int slot = tid + 256 * r;       // 0..511
        int row = slot >> 2;
        int gl = slot & 3;
        int gp = gl ^ (row & 3);
        size_t arow = (size_t)(unsigned)(perm[m0 + row] & (int)apmask);
        int kg = gl * 8;
        const float* ap = rbf + arow * 20 + kg;
        float4 v0 = make_float4(0.f, 0.f, 0.f, 0.f), v1 = v0;
        if (kg < 20) v0 = *(const float4*)ap;
        if (kg + 4 < 20) v1 = *(const float4*)(ap + 4);
        bf16 t[8] = {__float2bfloat16(v0.x), __float2bfloat16(v0.y),
                     __float2bfloat16(v0.z), __float2bfloat16(v0.w),
                     __float2bfloat16(v1.x), __float2bfloat16(v1.y),
                     __float2bfloat16(v1.z), __float2bfloat16(v1.w)};
        *(bf16x8*)(Ar + row * 32 + gp * 8) = *(const bf16x8*)t;
    }
    // ---- stage W1 [128][32] via gload, pre-swizzled source ----
#pragma unroll
    for (int i = 0; i < 2; ++i) {
        int row = wave * 32 + i * 16 + (lane >> 2);
        int gs = (lane & 3) ^ (row & 3);
        gload_lds16(W1t + row * 32 + gs * 8, W1 + (wave * 32 + i * 16) * 32);
    }
    __syncthreads();

    f32x4 acc[4][4];
#pragma unroll
    for (int i = 0; i < 4; ++i)
#pragma unroll
        for (int j = 0; j < 4; ++j) acc[i][j] = (f32x4){0.f, 0.f, 0.f, 0.f};

    // ---- GEMM1: K=32 (one MFMA chunk) ----
    {
        bf16x8 a[4], b[4];
#pragma unroll
        for (int i = 0; i < 4; ++i) {
            int row = wm + i * 16 + col16;
            a[i] = *(const bf16x8*)(Ar + row * 32 + (quad ^ (row & 3)) * 8);
        }
#pragma unroll
        for (int j = 0; j < 4; ++j) {
            int row = wn + j * 16 + col16;
            b[j] = *(const bf16x8*)(W1 + row * 32 + (quad ^ (row & 3)) * 8);
        }
#pragma unroll
        for (int i = 0; i < 4; ++i)
#pragma unroll
            for (int j = 0; j < 4; ++j)
                acc[i][j] = __builtin_amdgcn_mfma_f32_16x16x32_bf16(a[i], b[j], acc[i][j], 0, 0, 0);
    }
    // ---- silu -> Hs (swizzled scalar writes) ----
#pragma unroll
    for (int j = 0; j < 4; ++j) {
        int col = wn + j * 16 + col16;
        float bv = b1[col];
#pragma unroll
        for (int i = 0; i < 4; ++i) {
#pragma unroll
            for (int r = 0; r < 4; ++r) {
                int rowc = wm + i * 16 + quad * 4 + r;
                float v = silu_f(acc[i][j][r] + bv);
                Hs[rowc * 128 + (((col >> 3) ^ (rowc & 7)) << 3) + (col & 7)] =
                    __float2bfloat16(v);
            }
        }
    }
    // ---- stage W2 group 0 ----
#pragma unroll
    for (int i = 0; i < 8; ++i) {
        int row = wave * 32 + i * 4 + (lane >> 4);
        int gs = (lane & 15) ^ (row & 7);
        gload_lds16(W2t + (size_t)row * 128 + gs * 8, W2 + (wave * 32 + i * 4) * 128);
    }
    __syncthreads();

    for (int g = 0; g < 3; ++g) {
#pragma unroll
        for (int i = 0; i < 4; ++i)
#pragma unroll
            for (int j = 0; j < 4; ++j) acc[i][j] = (f32x4){0.f, 0.f, 0.f, 0.f};
#pragma unroll
        for (int s = 0; s < 4; ++s) {
            bf16x8 a[4], b[4];
#pragma unroll
            for (int i = 0; i < 4; ++i) {
                int row = wm + i * 16 + col16;
                a[i] = *(const bf16x8*)(Hs + row * 128 + ((s * 4 + quad) ^ (row & 7)) * 8);
            }
#pragma unroll
            for (int j = 0; j < 4; ++j) {
                int row = wn + j * 16 + col16;
                b[j] = *(const bf16x8*)(W2 + row * 128 + ((s * 4 + quad) ^ (row & 7)) * 8);
            }
#pragma unroll
            for (int i = 0; i < 4; ++i)
#pragma unroll
                for (int j = 0; j < 4; ++j)
                    acc[i][j] = __builtin_amdgcn_mfma_f32_16x16x32_bf16(a[i], b[j], acc[i][j], 0, 0, 0);
        }
        __syncthreads();   // W2/Hs reads done
        if (g < 2) {
#pragma unroll
            for (int i = 0; i < 8; ++i) {
                int row = wave * 32 + i * 4 + (lane >> 4);
                int gs = (lane & 15) ^ (row & 7);
                gload_lds16(W2t + (size_t)((g + 1) * 128 + row) * 128 + gs * 8,
                            W2 + (wave * 32 + i * 4) * 128);
            }
        }
        // ---- epilogue: +b2, *cutp -> filc ----
#pragma unroll
        for (int j = 0; j < 4; ++j) {
            int col = g * 128 + wn + j * 16 + col16;
            float bv = b2[col];
#pragma unroll
            for (int i = 0; i < 4; ++i) {
#pragma unroll
                for (int r = 0; r < 4; ++r) {
                    int row = m0 + wm + i * 16 + quad * 4 + r;
                    float v = (acc[i][j][r] + bv) * cutp[row];
                    filc[(size_t)row * 384 + col] = __float2bfloat16(v);
                }
            }
        }
        if (g < 2) __syncthreads();   // W2(g+1) staged
    }
}

// Fused weight transpose+convert for all 7 weights.
struct CvtArgs {
    const float* in[7];
    bf16* out[7];
    int K[7], Nc[7], Kp[7];
    int cum[8];
};
__global__ __launch_bounds__(256) void cvt_all(CvtArgs a)
{
    int i = blockIdx.x * 256 + threadIdx.x;
#pragma unroll
    for (int s = 0; s < 7; ++s) {
        if (i >= a.cum[s] && i < a.cum[s + 1]) {
            int j = i - a.cum[s];
            int n = j / a.Kp[s], k = j - n * a.Kp[s];
            a.out[s][j] = __float2bfloat16(
                k < a.K[s] ? a.in[s][(size_t)k * a.Nc[s] + n] : 0.f);
        }
    }
}

__global__ __launch_bounds__(256) void cvt_bf16(
    const float4* __restrict__ in, bf16* __restrict__ out, size_t n4)
{
    size_t i = (size_t)blockIdx.x * 256 + threadIdx.x;
    if (i >= n4) return;
    float4 v = in[i];
    bf16 t[4] = {__float2bfloat16(v.x), __float2bfloat16(v.y),
                 __float2bfloat16(v.z), __float2bfloat16(v.w)};
    *(bf16x4v*)(out + i * 4) = *(const bf16x4v*)t;
}

__global__ __launch_bounds__(256) void zero_k(float4* __restrict__ p, size_t n4)
{
    size_t i = (size_t)blockIdx.x * 256 + threadIdx.x;
    if (i < n4) p[i] = make_float4(0.f, 0.f, 0.f, 0.f);
}

// ---- counting sort by target ----
__global__ __launch_bounds__(256) void hist_k(
    const int* __restrict__ ei, int* __restrict__ hist, int E)
{
    int e = blockIdx.x * 256 + threadIdx.x;
    if (e < E) atomicAdd(&hist[ei[e]], 1);
}

// Single block, 256 threads, 128 targets each. Two regions: targets <16384
// start at 0, targets >=16384 start at SLOT1 (fixed slack base).
__global__ __launch_bounds__(256) void scan_k(
    const int* __restrict__ hist, int* __restrict__ off,
    int* __restrict__ cursor, int N, int SLOT1)
{
    __shared__ int ps[257];
    int tid = threadIdx.x;
    int base = tid * 128;
    int s = 0;
    for (int i = 0; i < 128; ++i) s += hist[base + i];
    ps[tid] = s;
    __syncthreads();
    if (tid == 0) {
        int run = 0;
        for (int i = 0; i < 256; ++i) { int t = ps[i]; ps[i] = run; run += t; }
        ps[256] = run;
    }
    __syncthreads();
    int T0 = ps[128];
    int run = ps[tid];
    for (int i = 0; i < 128; ++i) {
        int n = base + i;
        int o = (n < 16384) ? run : SLOT1 + run - T0;
        off[n] = o; cursor[n] = o;
        run += hist[n];
    }
    if (tid == 255) off[N] = SLOT1 + run - T0;
}

__global__ __launch_bounds__(256) void scatter_k(
    const int* __restrict__ ei, const float* __restrict__ uv,
    const float* __restrict__ cut, int* __restrict__ cursor,
    int* __restrict__ perm, int* __restrict__ srcp,
    float* __restrict__ cutp, float* __restrict__ uvp, int E)
{
    int e = blockIdx.x * 256 + threadIdx.x;
    if (e >= E) return;
    int tgt = ei[e];
    int pos = atomicAdd(&cursor[tgt], 1);
    perm[pos] = e;
    srcp[pos] = ei[E + e];
    cutp[pos] = cut[e];
    uvp[pos * 3 + 0] = uv[e * 3 + 0];
    uvp[pos * 3 + 1] = uv[e * 3 + 1];
    uvp[pos * 3 + 2] = uv[e * 3 + 2];
}

// ---- segmented edge reduction: one wave per target, unrolled x2 ----
// Segment length from hist (off[n+1] would cross region slack).
__global__ __launch_bounds__(256) void edge_seg(
    const bf16* __restrict__ x, const bf16* __restrict__ filt,
    const bf16* __restrict__ mub, const int* __restrict__ srcp,
    const float* __restrict__ uvp, const int* __restrict__ off,
    const int* __restrict__ hist,
    const float* __restrict__ q, const float* __restrict__ mu,
    float* __restrict__ outq, float* __restrict__ outmu,
    int t0, int tcount, int base)
{
    int t = blockIdx.x * 4 + (threadIdx.x >> 6);
    if (t >= tcount) return;
    int n = t0 + t;
    int lane = threadIdx.x & 63;
    int h = lane * 2;
    int p0 = off[n];
    int cnt = hist[n];
    int p1 = p0 + cnt;

    float aq0 = 0.f, aq1 = 0.f;
    float am00 = 0.f, am01 = 0.f, am10 = 0.f, am11 = 0.f, am20 = 0.f, am21 = 0.f;

#define EDGE_LOAD(P, S) \
    const bf16* fp##S = filt + (size_t)((P) - base) * 384; \
    int src##S = srcp[P]; \
    const bf16* xp##S = x + (size_t)src##S * 384; \
    const bf16* mp##S = mub + (size_t)src##S * 384; \
    __hip_bfloat162 fq##S = *(const __hip_bfloat162*)(fp##S + h); \
    __hip_bfloat162 fr##S = *(const __hip_bfloat162*)(fp##S + 128 + h); \
    __hip_bfloat162 fm##S = *(const __hip_bfloat162*)(fp##S + 256 + h); \
    __hip_bfloat162 xq##S = *(const __hip_bfloat162*)(xp##S + h); \
    __hip_bfloat162 xr##S = *(const __hip_bfloat162*)(xp##S + 128 + h); \
    __hip_bfloat162 xm##S = *(const __hip_bfloat162*)(xp##S + 256 + h); \
    __hip_bfloat162 m0##S = *(const __hip_bfloat162*)(mp##S + h); \
    __hip_bfloat162 m1##S = *(const __hip_bfloat162*)(mp##S + 128 + h); \
    __hip_bfloat162 m2##S = *(const __hip_bfloat162*)(mp##S + 256 + h); \
    float u0##S = uvp[(P) * 3 + 0]; \
    float u1##S = uvp[(P) * 3 + 1]; \
    float u2##S = uvp[(P) * 3 + 2];

#define EDGE_ACC(S) { \
    float xq0_ = __bfloat162float(xq##S.x) * __bfloat162float(fq##S.x); \
    float xq1_ = __bfloat162float(xq##S.y) * __bfloat162float(fq##S.y); \
    float xr0_ = __bfloat162float(xr##S.x) * __bfloat162float(fr##S.x); \
    float xr1_ = __bfloat162float(xr##S.y) * __bfloat162float(fr##S.y); \
    float xm0_ = __bfloat162float(xm##S.x) * __bfloat162float(fm##S.x); \
    float xm1_ = __bfloat162float(xm##S.y) * __bfloat162float(fm##S.y); \
    aq0 += xq0_; aq1 += xq1_; \
    am00 += fmaf(u0##S, xr0_, __bfloat162float(m0##S.x) * xm0_); \
    am01 += fmaf(u0##S, xr1_, __bfloat162float(m0##S.y) * xm1_); \
    am10 += fmaf(u1##S, xr0_, __bfloat162float(m1##S.x) * xm0_); \
    am11 += fmaf(u1##S, xr1_, __bfloat162float(m1##S.y) * xm1_); \
    am20 += fmaf(u2##S, xr0_, __bfloat162float(m2##S.x) * xm0_); \
    am21 += fmaf(u2##S, xr1_, __bfloat162float(m2##S.y) * xm1_); }

    int p = p0;
    for (; p + 2 <= p1; p += 2) {
        EDGE_LOAD(p, A)
        EDGE_LOAD(p + 1, B)
        EDGE_ACC(A)
        EDGE_ACC(B)
    }
    if (p < p1) {
        EDGE_LOAD(p, A)
        EDGE_ACC(A)
    }
#undef EDGE_LOAD
#undef EDGE_ACC

    float inv = 1.f / fmaxf((float)cnt, 1.f);
    size_t qb = (size_t)n * 128 + h;
    outq[qb]     = q[qb]     + aq0 * inv;
    outq[qb + 1] = q[qb + 1] + aq1 * inv;
    size_t mb = (size_t)n * 384 + h;
    outmu[mb]       = mu[mb]       + am00 * inv;
    outmu[mb + 1]   = mu[mb + 1]   + am01 * inv;
    outmu[mb + 128] = mu[mb + 128] + am10 * inv;
    outmu[mb + 129] = mu[mb + 129] + am11 * inv;
    outmu[mb + 256] = mu[mb + 256] + am20 * inv;
    outmu[mb + 257] = mu[mb + 257] + am21 * inv;
}

// mcat bf16 [3N][256] -> scin=[q|norm] bf16, inner f32. 2 channels/thread.
__global__ __launch_bounds__(256) void mix_pre(
    const bf16* __restrict__ mcat, const float* __restrict__ outq,
    bf16* __restrict__ scin, float* __restrict__ inner, int N)
{
    int i = blockIdx.x * 256 + threadIdx.x;
    if (i >= N * 64) return;
    int n = i >> 6;
    int h = (i & 63) * 2;
    size_t r = (size_t)n * 768;
    __hip_bfloat162 v0 = *(const __hip_bfloat162*)(mcat + r + h);
    __hip_bfloat162 w0 = *(const __hip_bfloat162*)(mcat + r + 128 + h);
    __hip_bfloat162 v1 = *(const __hip_bfloat162*)(mcat + r + 256 + h);
    __hip_bfloat162 w1 = *(const __hip_bfloat162*)(mcat + r + 384 + h);
    __hip_bfloat162 v2 = *(const __hip_bfloat162*)(mcat + r + 512 + h);
    __hip_bfloat162 w2 = *(const __hip_bfloat162*)(mcat + r + 640 + h);
    float v0x = __bfloat162float(v0.x), v0y = __bfloat162float(v0.y);
    float v1x = __bfloat162float(v1.x), v1y = __bfloat162float(v1.y);
    float v2x = __bfloat162float(v2.x), v2y = __bfloat162float(v2.y);
    float nx = sqrtf(v0x * v0x + v1x * v1x + v2x * v2x + 1e-8f);
    float ny = sqrtf(v0y * v0y + v1y * v1y + v2y * v2y + 1e-8f);
    float ix = v0x * __bfloat162float(w0.x) + v1x * __bfloat162float(w1.x)
             + v2x * __bfloat162float(w2.x);
    float iy = v0y * __bfloat162float(w0.y) + v1y * __bfloat162float(w1.y)
             + v2y * __bfloat162float(w2.y);
    *(float2*)(inner + (size_t)n * 128 + h) = make_float2(ix, iy);
    float2 qv = *(const float2*)(outq + (size_t)n * 128 + h);
    __hip_bfloat162 qb; qb.x = __float2bfloat16(qv.x); qb.y = __float2bfloat16(qv.y);
    __hip_bfloat162 nb; nb.x = __float2bfloat16(nx);  nb.y = __float2bfloat16(ny);
    *(__hip_bfloat162*)(scin + (size_t)n * 256 + h) = qb;
    *(__hip_bfloat162*)(scin + (size_t)n * 256 + 128 + h) = nb;
}

// q += dq + dqmu*inner ; mu += mu_w * dmu_scale. 2 channels/thread.
__global__ __launch_bounds__(256) void mix_post(
    const bf16* __restrict__ delta, const float* __restrict__ inner,
    const bf16* __restrict__ mcat,
    float* __restrict__ outq, float* __restrict__ outmu, int N)
{
    int i = blockIdx.x * 256 + threadIdx.x;
    if (i >= N * 64) return;
    int n = i >> 6;
    int h = (i & 63) * 2;
    size_t dr = (size_t)n * 384;
    __hip_bfloat162 dq2  = *(const __hip_bfloat162*)(delta + dr + h);
    __hip_bfloat162 ds2  = *(const __hip_bfloat162*)(delta + dr + 128 + h);
    __hip_bfloat162 dm2  = *(const __hip_bfloat162*)(delta + dr + 256 + h);
    float2 in2 = *(const float2*)(inner + (size_t)n * 128 + h);
    float2* oq = (float2*)(outq + (size_t)n * 128 + h);
    float2 qv = *oq;
    qv.x += __bfloat162float(dq2.x) + __bfloat162float(dm2.x) * in2.x;
    qv.y += __bfloat162float(dq2.y) + __bfloat162float(dm2.y) * in2.y;
    *oq = qv;
    float dsx = __bfloat162float(ds2.x), dsy = __bfloat162float(ds2.y);
    size_t r = (size_t)n * 768;
    size_t mb = (size_t)n * 384 + h;
    __hip_bfloat162 w0 = *(const __hip_bfloat162*)(mcat + r + 128 + h);
    __hip_bfloat162 w1 = *(const __hip_bfloat162*)(mcat + r + 384 + h);
    __hip_bfloat162 w2 = *(const __hip_bfloat162*)(mcat + r + 640 + h);
    float2* om0 = (float2*)(outmu + mb);
    float2* om1 = (float2*)(outmu + mb + 128);
    float2* om2 = (float2*)(outmu + mb + 256);
    float2 a0 = *om0, a1 = *om1, a2 = *om2;
    a0.x += __bfloat162float(w0.x) * dsx; a0.y += __bfloat162float(w0.y) * dsy;
    a1.x += __bfloat162float(w1.x) * dsx; a1.y += __bfloat162float(w1.y) * dsy;
    a2.x += __bfloat162float(w2.x) * dsx; a2.y += __bfloat162float(w2.y) * dsy;
    *om0 = a0; *om1 = a1; *om2 = a2;
}

extern "C" void kernel_launch(void* const* d_in, const int* in_sizes, int n_in,
                              void* d_out, int out_size, void* d_ws, size_t ws_size,
                              hipStream_t stream)
{
    const float* q   = (const float*)d_in[0];
    const float* mu  = (const float*)d_in[1];
    const int*   ei  = (const int*)d_in[2];
    const float* rbf = (const float*)d_in[3];
    const float* uv  = (const float*)d_in[4];
    const float* cut = (const float*)d_in[5];
    const float* Wi1 = (const float*)d_in[6];
    const float* bi1 = (const float*)d_in[7];
    const float* Wi2 = (const float*)d_in[8];
    const float* bi2 = (const float*)d_in[9];
    const float* Wf1 = (const float*)d_in[10];
    const float* bf1 = (const float*)d_in[11];
    const float* Wf2 = (const float*)d_in[12];
    const float* bf2 = (const float*)d_in[13];
    const float* Wv  = (const float*)d_in[14];
    const float* Ws1 = (const float*)d_in[15];
    const float* bs1 = (const float*)d_in[16];
    const float* Ws2 = (const float*)d_in[17];
    const float* bs2 = (const float*)d_in[18];

    const int H = 128;
    const int N = in_sizes[0] / H;   // 32768
    const int E = in_sizes[5];       // 262144
    const int SLOT1 = E / 2 + 4096;  // 135168, %128==0
    (void)n_in; (void)out_size;

    // ---- workspace layout (round-6 proven) ----
    char* ws = (char*)d_ws;
    size_t o = 0;
    auto take = [&](size_t b) { char* p = ws + o; o += (b + 255) & ~(size_t)255; return p; };
    bf16*  xb     = (bf16*)take((size_t)N * 384 * 2);        // 25.2 MB [P1..P3]
    bf16*  mub    = (bf16*)take((size_t)N * 384 * 2);        // 25.2 MB [P3]
    bf16*  filc   = (bf16*)take((size_t)SLOT1 * 384 * 2);    // 103.8 MB [P3]
    bf16*  hf     = (bf16*)take((size_t)SLOT1 * 128 * 2);    // 34.6 MB (unused now)
    int*   perm   = (int*)take((size_t)2 * SLOT1 * 4);
    int*   srcp   = (int*)take((size_t)2 * SLOT1 * 4);
    float* cutp   = (float*)take((size_t)2 * SLOT1 * 4);
    float* uvp    = (float*)take((size_t)2 * SLOT1 * 12);
    int*   hist   = (int*)take((size_t)N * 4);
    int*   off    = (int*)take((size_t)(N + 64) * 4);
    int*   cursor = (int*)take((size_t)N * 4);
    bf16*  wts    = (bf16*)take(1100000);
    if (o > ws_size) return;
    (void)hf;
    // P5 aliases (xb/mub/filc dead): 134.3 MB < 188.8 MB transient region
    bf16*  mcat  = (bf16*)ws;
    bf16*  scin  = mcat + (size_t)N * 768;
    float* inner = (float*)(scin + (size_t)N * 256);
    bf16*  s1    = (bf16*)(inner + (size_t)N * 128);
    bf16*  delta = s1 + (size_t)N * 384;

    bf16* Wi1t = wts;             // [384][128]
    bf16* Wi2t = Wi1t + 49152;    // [384][384]
    bf16* Wf1t = Wi2t + 147456;   // [128][32]
    bf16* Wf2t = Wf1t + 4096;     // [384][128]
    bf16* Wvt  = Wf2t + 49152;    // [256][128]
    bf16* Ws1t = Wvt  + 32768;    // [384][256]
    bf16* Ws2t = Ws1t + 98304;    // [384][384]

    float* outq  = (float*)d_out;
    float* outmu = outq + (size_t)N * 128;

    dim3 blk(256);

    // ---- P0: weights -> bf16 transposed; mu -> bf16 ----
    {
        CvtArgs a;
        const float* wi[7] = {Wi1, Wi2, Wf1, Wf2, Wv, Ws1, Ws2};
        bf16* wo[7] = {Wi1t, Wi2t, Wf1t, Wf2t, Wvt, Ws1t, Ws2t};
        int K[7]  = {128, 384, 20, 128, 128, 256, 384};
        int Nc[7] = {384, 384, 128, 384, 256, 384, 384};
        int Kp[7] = {128, 384, 32, 128, 128, 256, 384};
        int c = 0;
        for (int s = 0; s < 7; ++s) {
            a.in[s] = wi[s]; a.out[s] = wo[s];
            a.K[s] = K[s]; a.Nc[s] = Nc[s]; a.Kp[s] = Kp[s];
            a.cum[s] = c; c += Nc[s] * Kp[s];
        }
        a.cum[7] = c;
        cvt_all<<<dim3((c + 255) / 256), blk, 0, stream>>>(a);
        cvt_bf16<<<dim3((unsigned)((size_t)N * 384 / 4 / 256)), blk, 0, stream>>>(
            (const float4*)mu, mub, (size_t)N * 384 / 4);
    }

    // ---- P1: interaction MLP (full) ----
    {
        bf16* x1 = filc;   // scratch
        mgemm<float, bf16, 1><<<dim3(N / 128, 3), blk, 0, stream>>>(
            q, Wi1t, bi1, nullptr, x1, N, 128, 384, 128);
        mgemm<bf16, bf16, 0><<<dim3(N / 128, 3), blk, 0, stream>>>(
            x1, Wi2t, bi2, nullptr, xb, N, 384, 384, 0);
    }

    // ---- PS: counting sort by target ----
    zero_k<<<dim3((N / 4 + 255) / 256), blk, 0, stream>>>((float4*)hist, N / 4);
    hist_k<<<dim3(E / 256), blk, 0, stream>>>(ei, hist, E);
    scan_k<<<dim3(1), blk, 0, stream>>>(hist, off, cursor, N, SLOT1);
    scatter_k<<<dim3(E / 256), blk, 0, stream>>>(ei, uv, cut, cursor,
                                                 perm, srcp, cutp, uvp, E);

    // ---- P3: fused filter pipeline + segmented edge reduce, 2 chunks ----
    for (int c = 0; c < 2; ++c) {
        int base = c * SLOT1;
        fil_fused<<<dim3(SLOT1 / 128), blk, 0, stream>>>(
            rbf, Wf1t, bf1, Wf2t, bf2, cutp + base, perm + base, filc,
            (unsigned)(E - 1));
        edge_seg<<<dim3(16384 / 4), blk, 0, stream>>>(
            xb, filc, mub, srcp, uvp, off, hist, q, mu, outq, outmu,
            c * 16384, 16384, base);
    }

    // ---- P5: mixing (full) ----
    mgemm<float, bf16, 0><<<dim3(3 * N / 128, 2), blk, 0, stream>>>(
        outmu, Wvt, nullptr, nullptr, mcat, 3 * N, 128, 256, 128);
    mix_pre<<<dim3(N * 64 / 256), blk, 0, stream>>>(mcat, outq, scin, inner, N);
    mgemm<bf16, bf16, 1><<<dim3(N / 128, 3), blk, 0, stream>>>(
        scin, Ws1t, bs1, nullptr, s1, N, 256, 384, 0);
    mgemm<bf16, bf16, 0><<<dim3(N / 128, 3), blk, 0, stream>>>(
        s1, Ws2t, bs2, nullptr, delta, N, 384, 384, 0);
    mix_post<<<dim3(N * 64 / 256), blk, 0, stream>>>(delta, inner, mcat,
                                                     outq, outmu, N);
}